// Round 1
// baseline (62.380 us; speedup 1.0000x reference)
//
#include <hip/hip_runtime.h>
#include <hip/hip_bf16.h>

#define N 4096
#define D 768
#define INV_T 20.0f

typedef __attribute__((ext_vector_type(8))) short bf16x8;
typedef __attribute__((ext_vector_type(4))) float f32x4;

// ws layout (bytes):
//   [0,        6291456)  A bf16 (anchors * INV_T), N*D
//   [6291456, 12582912)  B bf16 (positives), N*D
//   [12582912,13107200)  partial[32][4096] float  (per colTile row sums of exp)
//   [13107200,13123584)  diagS[4096] float        (scaled logit s_jj)
//   [13123584,13139968)  lastS[4096] float        (scaled logit s_{j,N-1})
//   [13139968,13140096)  blockSums[32] float

__device__ inline ushort f2bf(float x) {
    union { float f; unsigned u; } v; v.f = x;
    unsigned r = (v.u + 0x7fffu + ((v.u >> 16) & 1u)) >> 16;
    return (ushort)r;
}

__global__ void convert_kernel(const float* __restrict__ A, const float* __restrict__ B,
                               ushort* __restrict__ Abf, ushort* __restrict__ Bbf) {
    const int total = N * D / 4;
    int idx = blockIdx.x * blockDim.x + threadIdx.x;
    int stride = gridDim.x * blockDim.x;
    for (int i = idx; i < total; i += stride) {
        float4 a = ((const float4*)A)[i];
        float4 b = ((const float4*)B)[i];
        ushort4 av, bv;
        av.x = f2bf(a.x * INV_T); av.y = f2bf(a.y * INV_T);
        av.z = f2bf(a.z * INV_T); av.w = f2bf(a.w * INV_T);
        bv.x = f2bf(b.x); bv.y = f2bf(b.y); bv.z = f2bf(b.z); bv.w = f2bf(b.w);
        ((ushort4*)Abf)[i] = av;
        ((ushort4*)Bbf)[i] = bv;
    }
}

// 128x128 tile, BK=32, 4 waves (2x2), each wave 64x64 = 4x4 frags of 16x16x32.
__global__ __launch_bounds__(256) void gemm_kernel(const ushort* __restrict__ Abf,
                                                   const ushort* __restrict__ Bbf,
                                                   float* __restrict__ partial,
                                                   float* __restrict__ diagS,
                                                   float* __restrict__ lastS) {
    __shared__ __align__(16) ushort As[128][40];  // +8 pad: stride 80B, conflict-free
    __shared__ __align__(16) ushort Bs[128][40];
    __shared__ float rowsum[128];

    const int t    = threadIdx.x;
    const int bCol = blockIdx.x;
    const int bRow = blockIdx.y;
    const int lane = t & 63;
    const int w    = t >> 6;
    const int wr   = w >> 1;      // wave row 0..1
    const int wc   = w & 1;       // wave col 0..1
    const int lr   = lane & 15;   // row/col within fragment
    const int lkb  = (lane >> 4) * 8;  // k offset within fragment

    if (t < 128) rowsum[t] = 0.0f;

    f32x4 acc[4][4] = {};

    const int sr = t >> 2;        // staging row 0..63
    const int sc = (t & 3) * 8;   // staging col 0,8,16,24

    const size_t aBase = (size_t)(bRow * 128) * D;
    const size_t bBase = (size_t)(bCol * 128) * D;

    for (int k0 = 0; k0 < D; k0 += 32) {
        __syncthreads();
        *(uint4*)&As[sr][sc]      = *(const uint4*)&Abf[aBase + (size_t)sr * D + k0 + sc];
        *(uint4*)&As[sr + 64][sc] = *(const uint4*)&Abf[aBase + (size_t)(sr + 64) * D + k0 + sc];
        *(uint4*)&Bs[sr][sc]      = *(const uint4*)&Bbf[bBase + (size_t)sr * D + k0 + sc];
        *(uint4*)&Bs[sr + 64][sc] = *(const uint4*)&Bbf[bBase + (size_t)(sr + 64) * D + k0 + sc];
        __syncthreads();

        bf16x8 af[4], bf[4];
        #pragma unroll
        for (int m = 0; m < 4; ++m) af[m] = *(const bf16x8*)&As[wr * 64 + m * 16 + lr][lkb];
        #pragma unroll
        for (int n = 0; n < 4; ++n) bf[n] = *(const bf16x8*)&Bs[wc * 64 + n * 16 + lr][lkb];
        #pragma unroll
        for (int m = 0; m < 4; ++m)
            #pragma unroll
            for (int n = 0; n < 4; ++n)
                acc[m][n] = __builtin_amdgcn_mfma_f32_16x16x32_bf16(af[m], bf[n], acc[m][n], 0, 0, 0);
    }

    // C/D layout (verified m89): col = lane&15, row = (lane>>4)*4 + reg
    const int rifb = (lane >> 4) * 4;  // row-in-frag base

    // diagonal capture: s_jj lives in frags (m,m) of waves with wr==wc
    if (bRow == bCol && wr == wc) {
        #pragma unroll
        for (int m = 0; m < 4; ++m)
            #pragma unroll
            for (int reg = 0; reg < 4; ++reg)
                if (lr == rifb + reg)
                    diagS[bRow * 128 + wr * 64 + m * 16 + rifb + reg] = acc[m][m][reg];
    }

    // last-column capture: global col N-1 -> bCol==31, wc==1, n==3, lr==15
    if (bCol == (N / 128 - 1) && wc == 1 && lr == 15) {
        #pragma unroll
        for (int m = 0; m < 4; ++m)
            #pragma unroll
            for (int reg = 0; reg < 4; ++reg)
                lastS[bRow * 128 + wr * 64 + m * 16 + rifb + reg] = acc[m][3][reg];
    }

    // exp + row-sum over this tile's 128 columns
    #pragma unroll
    for (int m = 0; m < 4; ++m) {
        #pragma unroll
        for (int reg = 0; reg < 4; ++reg) {
            float s = __expf(acc[m][0][reg]) + __expf(acc[m][1][reg]) +
                      __expf(acc[m][2][reg]) + __expf(acc[m][3][reg]);
            s += __shfl_xor(s, 1);
            s += __shfl_xor(s, 2);
            s += __shfl_xor(s, 4);
            s += __shfl_xor(s, 8);
            if (lr == 0) atomicAdd(&rowsum[wr * 64 + m * 16 + rifb + reg], s);
        }
    }
    __syncthreads();
    if (t < 128) partial[(size_t)bCol * N + bRow * 128 + t] = rowsum[t];
}

__global__ void rowloss_kernel(const float* __restrict__ partial, const float* __restrict__ diagS,
                               const float* __restrict__ lastS, float* __restrict__ blockSums) {
    const int j = blockIdx.x * 128 + threadIdx.x;
    float rs = 0.0f;
    #pragma unroll
    for (int tI = 0; tI < 32; ++tI) rs += partial[(size_t)tI * N + j];
    float denom = rs + __expf(diagS[j]);
    float lossj = __logf(denom) - lastS[j];
    #pragma unroll
    for (int off = 1; off < 64; off <<= 1) lossj += __shfl_xor(lossj, off);
    __shared__ float ws2[2];
    if ((threadIdx.x & 63) == 0) ws2[threadIdx.x >> 6] = lossj;
    __syncthreads();
    if (threadIdx.x == 0) blockSums[blockIdx.x] = ws2[0] + ws2[1];
}

__global__ void final_kernel(const float* __restrict__ blockSums, float* __restrict__ out) {
    float v = (threadIdx.x < 32) ? blockSums[threadIdx.x] : 0.0f;
    #pragma unroll
    for (int off = 1; off < 32; off <<= 1) v += __shfl_xor(v, off);
    if (threadIdx.x == 0) out[0] = v;
}

extern "C" void kernel_launch(void* const* d_in, const int* in_sizes, int n_in,
                              void* d_out, int out_size, void* d_ws, size_t ws_size,
                              hipStream_t stream) {
    const float* A = (const float*)d_in[0];
    const float* B = (const float*)d_in[1];
    float* out = (float*)d_out;
    char* ws = (char*)d_ws;

    ushort* Abf      = (ushort*)(ws);
    ushort* Bbf      = (ushort*)(ws + 6291456);
    float*  partial  = (float*)(ws + 12582912);
    float*  diagS    = (float*)(ws + 13107200);
    float*  lastS    = (float*)(ws + 13123584);
    float*  blockSums= (float*)(ws + 13139968);

    convert_kernel<<<1024, 256, 0, stream>>>(A, B, Abf, Bbf);
    gemm_kernel<<<dim3(32, 32), 256, 0, stream>>>(Abf, Bbf, partial, diagS, lastS);
    rowloss_kernel<<<32, 128, 0, stream>>>(partial, diagS, lastS, blockSums);
    final_kernel<<<1, 64, 0, stream>>>(blockSums, out);
}

// Round 3
// 50.442 us; speedup vs baseline: 1.2367x; 1.2367x over previous
//
#include <hip/hip_runtime.h>
#include <hip/hip_bf16.h>

#define N 4096
#define D 768
#define LOG2E 1.44269504088896340736f
#define A_SCALE (20.0f * LOG2E)   // INV_T * log2(e): puts logits in base-2 domain
#define LN2 0.69314718055994530942f

typedef __attribute__((ext_vector_type(8))) short bf16x8;
typedef __attribute__((ext_vector_type(4))) float f32x4;

#define EXP2F(x) __builtin_amdgcn_exp2f(x)   // v_exp_f32: 2^x
#define LOG2F(x) __builtin_amdgcn_logf(x)    // v_log_f32: log2(x)

// global -> LDS direct DMA, 16B per lane, linear dest (wave base + lane*16)
#define GLDS16(g, l) __builtin_amdgcn_global_load_lds( \
    (const __attribute__((address_space(1))) void*)(g), \
    (__attribute__((address_space(3))) void*)(l), 16, 0, 0)

// ws layout (bytes):
//   [0,        6291456)  A bf16 (anchors * INV_T * log2e), N*D
//   [6291456, 12582912)  B bf16 (positives), N*D
//   [12582912,13107200)  partial[32][4096] float  (per colTile row sums of 2^s)
//   [13107200,13123584)  diagS[4096] float        (s2_jj, base-2 logit)
//   [13123584,13139968)  lastS[4096] float        (s2_{j,N-1})
//   [13139968,13140096)  blockSums[32] float

__device__ inline ushort f2bf(float x) {
    union { float f; unsigned u; } v; v.f = x;
    unsigned r = (v.u + 0x7fffu + ((v.u >> 16) & 1u)) >> 16;
    return (ushort)r;
}

__global__ void convert_kernel(const float* __restrict__ A, const float* __restrict__ B,
                               ushort* __restrict__ Abf, ushort* __restrict__ Bbf) {
    const int total = N * D / 4;
    int idx = blockIdx.x * blockDim.x + threadIdx.x;
    int stride = gridDim.x * blockDim.x;
    for (int i = idx; i < total; i += stride) {
        float4 a = ((const float4*)A)[i];
        float4 b = ((const float4*)B)[i];
        ushort4 av, bv;
        av.x = f2bf(a.x * A_SCALE); av.y = f2bf(a.y * A_SCALE);
        av.z = f2bf(a.z * A_SCALE); av.w = f2bf(a.w * A_SCALE);
        bv.x = f2bf(b.x); bv.y = f2bf(b.y); bv.z = f2bf(b.z); bv.w = f2bf(b.w);
        ((ushort4*)Abf)[i] = av;
        ((ushort4*)Bbf)[i] = bv;
    }
}

// 128x128 tile, BK=64, 4 waves (2x2), each wave 64x64 = 4x4 frags of 16x16x32.
// LDS is linear [128][64] (global_load_lds requirement); bank conflicts killed
// by XOR-swizzle: LDS chunk c of row r holds global chunk c ^ (r&7), and the
// fragment ds_read applies the same XOR (rule #21: both-sides-or-neither).
__global__ __launch_bounds__(256) void gemm_kernel(const ushort* __restrict__ Abf,
                                                   const ushort* __restrict__ Bbf,
                                                   float* __restrict__ partial,
                                                   float* __restrict__ diagS,
                                                   float* __restrict__ lastS) {
    __shared__ __align__(16) ushort As[128 * 64];  // 16 KB
    __shared__ __align__(16) ushort Bs[128 * 64];  // 16 KB
    __shared__ float rowsum2[2][128];

    const int t    = threadIdx.x;
    const int bCol = blockIdx.x;
    const int bRow = blockIdx.y;
    const int lane = t & 63;
    const int w    = t >> 6;
    const int wr   = w >> 1;
    const int wc   = w & 1;
    const int lr   = lane & 15;
    const int hi   = lane >> 4;

    // staging: thread t covers (row sr32 + inst*32, 16B chunk sc) of the tile;
    // source chunk is XOR-swizzled so the linear LDS image is the swizzled layout
    const int sr32 = t >> 3;            // 0..31
    const int sc   = t & 7;             // 0..7
    const int gcv  = sc ^ (sr32 & 7);   // swizzled global chunk
    const size_t aOff = (size_t)(bRow * 128 + sr32) * D + gcv * 8;
    const size_t bOff = (size_t)(bCol * 128 + sr32) * D + gcv * 8;

    f32x4 acc[4][4] = {};

    for (int k0 = 0; k0 < D; k0 += 64) {
        __syncthreads();
        #pragma unroll
        for (int inst = 0; inst < 4; ++inst) {
            GLDS16(Abf + aOff + (size_t)inst * 32 * D + k0, &As[inst * 2048 + w * 512]);
            GLDS16(Bbf + bOff + (size_t)inst * 32 * D + k0, &Bs[inst * 2048 + w * 512]);
        }
        __syncthreads();  // compiler drains vmcnt(0) here

        #pragma unroll
        for (int kk = 0; kk < 2; ++kk) {
            bf16x8 af[4], bfr[4];
            #pragma unroll
            for (int m = 0; m < 4; ++m) {
                const int R = wr * 64 + m * 16 + lr;
                af[m] = *(const bf16x8*)&As[R * 64 + (((kk * 4 + hi) ^ (lr & 7)) * 8)];
            }
            #pragma unroll
            for (int n = 0; n < 4; ++n) {
                const int R = wc * 64 + n * 16 + lr;
                bfr[n] = *(const bf16x8*)&Bs[R * 64 + (((kk * 4 + hi) ^ (lr & 7)) * 8)];
            }
            #pragma unroll
            for (int m = 0; m < 4; ++m)
                #pragma unroll
                for (int n = 0; n < 4; ++n)
                    acc[m][n] = __builtin_amdgcn_mfma_f32_16x16x32_bf16(af[m], bfr[n], acc[m][n], 0, 0, 0);
        }
    }

    // C/D layout (m89): col = lane&15 (= lr), row = hi*4 + reg
    const int rifb = hi * 4;

    if (bRow == bCol && wr == wc) {
        #pragma unroll
        for (int m = 0; m < 4; ++m)
            #pragma unroll
            for (int reg = 0; reg < 4; ++reg)
                if (lr == rifb + reg)
                    diagS[bRow * 128 + wr * 64 + m * 16 + rifb + reg] = acc[m][m][reg];
    }

    if (bCol == (N / 128 - 1) && wc == 1 && lr == 15) {
        #pragma unroll
        for (int m = 0; m < 4; ++m)
            #pragma unroll
            for (int reg = 0; reg < 4; ++reg)
                lastS[bRow * 128 + wr * 64 + m * 16 + rifb + reg] = acc[m][3][reg];
    }

    // 2^s over the tile, row-sum across the wave's 64 columns
    #pragma unroll
    for (int m = 0; m < 4; ++m) {
        #pragma unroll
        for (int reg = 0; reg < 4; ++reg) {
            float s = EXP2F(acc[m][0][reg]) + EXP2F(acc[m][1][reg]) +
                      EXP2F(acc[m][2][reg]) + EXP2F(acc[m][3][reg]);
            s += __shfl_xor(s, 1);
            s += __shfl_xor(s, 2);
            s += __shfl_xor(s, 4);
            s += __shfl_xor(s, 8);
            if (lr == 0) rowsum2[wc][wr * 64 + m * 16 + rifb + reg] = s;
        }
    }
    __syncthreads();
    if (t < 128) partial[(size_t)bCol * N + bRow * 128 + t] = rowsum2[0][t] + rowsum2[1][t];
}

__global__ void rowloss_kernel(const float* __restrict__ partial, const float* __restrict__ diagS,
                               const float* __restrict__ lastS, float* __restrict__ blockSums) {
    const int j = blockIdx.x * 128 + threadIdx.x;
    float rs = 0.0f;
    #pragma unroll
    for (int tI = 0; tI < 32; ++tI) rs += partial[(size_t)tI * N + j];
    float denom = rs + EXP2F(diagS[j]);
    float lossj = LN2 * (LOG2F(denom) - lastS[j]);
    #pragma unroll
    for (int off = 1; off < 64; off <<= 1) lossj += __shfl_xor(lossj, off);
    __shared__ float ws2[2];
    if ((threadIdx.x & 63) == 0) ws2[threadIdx.x >> 6] = lossj;
    __syncthreads();
    if (threadIdx.x == 0) blockSums[blockIdx.x] = ws2[0] + ws2[1];
}

__global__ void final_kernel(const float* __restrict__ blockSums, float* __restrict__ out) {
    float v = (threadIdx.x < 32) ? blockSums[threadIdx.x] : 0.0f;
    #pragma unroll
    for (int off = 1; off < 32; off <<= 1) v += __shfl_xor(v, off);
    if (threadIdx.x == 0) out[0] = v;
}

extern "C" void kernel_launch(void* const* d_in, const int* in_sizes, int n_in,
                              void* d_out, int out_size, void* d_ws, size_t ws_size,
                              hipStream_t stream) {
    const float* A = (const float*)d_in[0];
    const float* B = (const float*)d_in[1];
    float* out = (float*)d_out;
    char* ws = (char*)d_ws;

    ushort* Abf      = (ushort*)(ws);
    ushort* Bbf      = (ushort*)(ws + 6291456);
    float*  partial  = (float*)(ws + 12582912);
    float*  diagS    = (float*)(ws + 13107200);
    float*  lastS    = (float*)(ws + 13123584);
    float*  blockSums= (float*)(ws + 13139968);

    convert_kernel<<<1024, 256, 0, stream>>>(A, B, Abf, Bbf);
    gemm_kernel<<<dim3(32, 32), 256, 0, stream>>>(Abf, Bbf, partial, diagS, lastS);
    rowloss_kernel<<<32, 128, 0, stream>>>(partial, diagS, lastS, blockSums);
    final_kernel<<<1, 64, 0, stream>>>(blockSums, out);
}